// Round 1
// baseline (432.924 us; speedup 1.0000x reference)
//
#include <hip/hip_runtime.h>
#include <math.h>

#define T_DIM 2048
#define B_DIM 32
#define H_DIM 1024

// ---------------------------------------------------------------------------
// Kernel 1: v[b,h] = sum_k hidden[b,k] * W[k,h]
// grid = (H/256, B), block = 256. Coalesced W rows; hidden staged in LDS
// (broadcast reads, conflict-free).
// ---------------------------------------------------------------------------
__global__ void __launch_bounds__(256) compute_v_kernel(
    const float* __restrict__ hidden,
    const float* __restrict__ W,
    float* __restrict__ v) {
    const int b = blockIdx.y;
    const int h = blockIdx.x * 256 + threadIdx.x;

    __shared__ float hsh[H_DIM];
    #pragma unroll
    for (int i = 0; i < H_DIM / 256; ++i)
        hsh[i * 256 + threadIdx.x] = hidden[b * H_DIM + i * 256 + threadIdx.x];
    __syncthreads();

    float acc = 0.f;
    #pragma unroll 8
    for (int k = 0; k < H_DIM; ++k)
        acc = fmaf(hsh[k], W[(size_t)k * H_DIM + h], acc);

    v[b * H_DIM + h] = acc;
}

// ---------------------------------------------------------------------------
// Kernel 2: scores[b,t] = enc[t,b,:] . v[b,:]
// grid = (T/4, B), block = 256 (4 waves; one wave per t-row).
// enc row read as float4 (16 B/lane, coalesced); v[b] staged in LDS once
// per block. Wave shuffle-reduce for the dot.
// ---------------------------------------------------------------------------
__global__ void __launch_bounds__(256) compute_scores_kernel(
    const float* __restrict__ enc,
    const float* __restrict__ v,
    float* __restrict__ scores) {
    const int b    = blockIdx.y;
    const int wave = threadIdx.x >> 6;
    const int lane = threadIdx.x & 63;
    const int t    = blockIdx.x * 4 + wave;

    __shared__ float vsh[H_DIM];
    {
        const float4* src = (const float4*)(v + b * H_DIM);
        float4*       dst = (float4*)vsh;
        dst[threadIdx.x] = src[threadIdx.x];  // 256 threads x 16 B = 4 KB
    }
    __syncthreads();

    const float4* row = (const float4*)(enc + ((size_t)t * B_DIM + b) * H_DIM);
    const float4* vv4 = (const float4*)vsh;

    float acc = 0.f;
    #pragma unroll
    for (int p = 0; p < H_DIM / (64 * 4); ++p) {  // 4 passes
        float4 e = row[p * 64 + lane];
        float4 w = vv4[p * 64 + lane];
        acc = fmaf(e.x, w.x, acc);
        acc = fmaf(e.y, w.y, acc);
        acc = fmaf(e.z, w.z, acc);
        acc = fmaf(e.w, w.w, acc);
    }

    #pragma unroll
    for (int off = 32; off > 0; off >>= 1)
        acc += __shfl_down(acc, off, 64);

    if (lane == 0) scores[b * T_DIM + t] = acc;
}

// ---------------------------------------------------------------------------
// Kernel 3: out[b,0,:] = softmax(scores[b,:])  — one block per b.
// ---------------------------------------------------------------------------
__global__ void __launch_bounds__(256) softmax_kernel(
    const float* __restrict__ scores,
    float* __restrict__ out) {
    const int b    = blockIdx.x;
    const int tid  = threadIdx.x;
    const int lane = tid & 63;
    const int wv   = tid >> 6;

    const float* row = scores + b * T_DIM;
    float vals[T_DIM / 256];

    float lmax = -INFINITY;
    #pragma unroll
    for (int i = 0; i < T_DIM / 256; ++i) {
        vals[i] = row[i * 256 + tid];
        lmax = fmaxf(lmax, vals[i]);
    }

    __shared__ float redm[4];
    #pragma unroll
    for (int off = 32; off > 0; off >>= 1)
        lmax = fmaxf(lmax, __shfl_xor(lmax, off, 64));
    if (lane == 0) redm[wv] = lmax;
    __syncthreads();
    const float bmax = fmaxf(fmaxf(redm[0], redm[1]), fmaxf(redm[2], redm[3]));

    float lsum = 0.f;
    #pragma unroll
    for (int i = 0; i < T_DIM / 256; ++i) {
        vals[i] = expf(vals[i] - bmax);
        lsum += vals[i];
    }

    __shared__ float reds[4];
    #pragma unroll
    for (int off = 32; off > 0; off >>= 1)
        lsum += __shfl_xor(lsum, off, 64);
    if (lane == 0) reds[wv] = lsum;
    __syncthreads();
    const float inv = 1.0f / (reds[0] + reds[1] + reds[2] + reds[3]);

    #pragma unroll
    for (int i = 0; i < T_DIM / 256; ++i)
        out[b * T_DIM + i * 256 + tid] = vals[i] * inv;
}

// ---------------------------------------------------------------------------
// Inputs (setup_inputs order): hidden [1,B,H] f32, encoderOutput [T,B,H] f32,
// W [H,H] f32, b [H] f32 (unused: cancels in softmax).
// Output: [B,1,T] f32.
// Workspace layout: v (B*H f32) @ 0, scores (B*T f32) @ 128 KiB.
// ---------------------------------------------------------------------------
extern "C" void kernel_launch(void* const* d_in, const int* in_sizes, int n_in,
                              void* d_out, int out_size, void* d_ws, size_t ws_size,
                              hipStream_t stream) {
    const float* hidden = (const float*)d_in[0];
    const float* enc    = (const float*)d_in[1];
    const float* W      = (const float*)d_in[2];
    float* out = (float*)d_out;

    float* v      = (float*)d_ws;                        // 32*1024 f32 = 128 KiB
    float* scores = (float*)((char*)d_ws + (size_t)B_DIM * H_DIM * sizeof(float));

    compute_v_kernel<<<dim3(H_DIM / 256, B_DIM), 256, 0, stream>>>(hidden, W, v);
    compute_scores_kernel<<<dim3(T_DIM / 4, B_DIM), 256, 0, stream>>>(enc, v, scores);
    softmax_kernel<<<B_DIM, 256, 0, stream>>>(scores, out);
}

// Round 2
// 396.117 us; speedup vs baseline: 1.0929x; 1.0929x over previous
//
#include <hip/hip_runtime.h>
#include <math.h>

#define T_DIM 2048
#define B_DIM 32
#define H_DIM 1024
#define KSPLIT 8
#define KCHUNK (H_DIM / KSPLIT)  // 128

// ---------------------------------------------------------------------------
// Kernel 1: v[b,h] += sum_{k in chunk} hidden[b,k] * W[k,h]   (split-K)
// grid = (H/256, B, KSPLIT) = (4,32,8) = 1024 blocks, block = 256.
// 16 waves/CU -> latency hidden. hidden[b,k] is a wave-uniform broadcast load.
// v must be zeroed before launch (hipMemsetAsync in kernel_launch).
// ---------------------------------------------------------------------------
__global__ void __launch_bounds__(256) compute_v_kernel(
    const float* __restrict__ hidden,
    const float* __restrict__ W,
    float* __restrict__ v) {
    const int b  = blockIdx.y;
    const int h  = blockIdx.x * 256 + threadIdx.x;
    const int k0 = blockIdx.z * KCHUNK;
    const float* hrow = hidden + b * H_DIM + k0;
    const float* wcol = W + (size_t)k0 * H_DIM + h;

    float acc = 0.f;
    #pragma unroll 16
    for (int k = 0; k < KCHUNK; ++k)
        acc = fmaf(hrow[k], wcol[(size_t)k * H_DIM], acc);

    atomicAdd(&v[b * H_DIM + h], acc);
}

// ---------------------------------------------------------------------------
// Kernel 2: scores[b,t] = enc[t,b,:] . v[b,:]
// grid = (T/8, B) = (256,32) = 8192 blocks, block = 256 (4 waves).
// Each wave computes TWO t-rows: one LDS v-read feeds two enc rows (2x MLP).
// enc rows read as float4 (16 B/lane, fully coalesced 1 KB/wave/instr).
// ---------------------------------------------------------------------------
__global__ void __launch_bounds__(256) compute_scores_kernel(
    const float* __restrict__ enc,
    const float* __restrict__ v,
    float* __restrict__ scores) {
    const int b    = blockIdx.y;
    const int wave = threadIdx.x >> 6;
    const int lane = threadIdx.x & 63;
    const int t0   = blockIdx.x * 8 + wave * 2;  // this wave's two rows: t0, t0+1

    __shared__ float vsh[H_DIM];
    {
        const float4* src = (const float4*)(v + b * H_DIM);
        ((float4*)vsh)[threadIdx.x] = src[threadIdx.x];  // 4 KB
    }
    __syncthreads();

    const float4* row0 = (const float4*)(enc + ((size_t)t0 * B_DIM + b) * H_DIM);
    const float4* row1 = row0 + (B_DIM * H_DIM) / 4;  // t0+1
    const float4* vv4  = (const float4*)vsh;

    float acc0 = 0.f, acc1 = 0.f;
    #pragma unroll
    for (int p = 0; p < H_DIM / (64 * 4); ++p) {  // 4 passes over the row
        const float4 w  = vv4[p * 64 + lane];
        const float4 e0 = row0[p * 64 + lane];
        const float4 e1 = row1[p * 64 + lane];
        acc0 = fmaf(e0.x, w.x, acc0); acc1 = fmaf(e1.x, w.x, acc1);
        acc0 = fmaf(e0.y, w.y, acc0); acc1 = fmaf(e1.y, w.y, acc1);
        acc0 = fmaf(e0.z, w.z, acc0); acc1 = fmaf(e1.z, w.z, acc1);
        acc0 = fmaf(e0.w, w.w, acc0); acc1 = fmaf(e1.w, w.w, acc1);
    }

    #pragma unroll
    for (int off = 32; off > 0; off >>= 1) {
        acc0 += __shfl_down(acc0, off, 64);
        acc1 += __shfl_down(acc1, off, 64);
    }

    if (lane == 0) {
        scores[b * T_DIM + t0]     = acc0;
        scores[b * T_DIM + t0 + 1] = acc1;
    }
}

// ---------------------------------------------------------------------------
// Kernel 3: out[b,0,:] = softmax(scores[b,:]) — one block per b.
// ---------------------------------------------------------------------------
__global__ void __launch_bounds__(256) softmax_kernel(
    const float* __restrict__ scores,
    float* __restrict__ out) {
    const int b    = blockIdx.x;
    const int tid  = threadIdx.x;
    const int lane = tid & 63;
    const int wv   = tid >> 6;

    const float* row = scores + b * T_DIM;
    float vals[T_DIM / 256];

    float lmax = -INFINITY;
    #pragma unroll
    for (int i = 0; i < T_DIM / 256; ++i) {
        vals[i] = row[i * 256 + tid];
        lmax = fmaxf(lmax, vals[i]);
    }

    __shared__ float redm[4];
    #pragma unroll
    for (int off = 32; off > 0; off >>= 1)
        lmax = fmaxf(lmax, __shfl_xor(lmax, off, 64));
    if (lane == 0) redm[wv] = lmax;
    __syncthreads();
    const float bmax = fmaxf(fmaxf(redm[0], redm[1]), fmaxf(redm[2], redm[3]));

    float lsum = 0.f;
    #pragma unroll
    for (int i = 0; i < T_DIM / 256; ++i) {
        vals[i] = expf(vals[i] - bmax);
        lsum += vals[i];
    }

    __shared__ float reds[4];
    #pragma unroll
    for (int off = 32; off > 0; off >>= 1)
        lsum += __shfl_xor(lsum, off, 64);
    if (lane == 0) reds[wv] = lsum;
    __syncthreads();
    const float inv = 1.0f / (reds[0] + reds[1] + reds[2] + reds[3]);

    #pragma unroll
    for (int i = 0; i < T_DIM / 256; ++i)
        out[b * T_DIM + i * 256 + tid] = vals[i] * inv;
}

// ---------------------------------------------------------------------------
// Inputs: hidden [1,B,H] f32, encoderOutput [T,B,H] f32, W [H,H] f32,
// bias [H] f32 (unused: constant per softmax row, cancels exactly).
// Output: [B,1,T] f32.
// Workspace: v (B*H f32, zeroed each call) @ 0, scores (B*T f32) @ 128 KiB.
// ---------------------------------------------------------------------------
extern "C" void kernel_launch(void* const* d_in, const int* in_sizes, int n_in,
                              void* d_out, int out_size, void* d_ws, size_t ws_size,
                              hipStream_t stream) {
    const float* hidden = (const float*)d_in[0];
    const float* enc    = (const float*)d_in[1];
    const float* W      = (const float*)d_in[2];
    float* out = (float*)d_out;

    float* v      = (float*)d_ws;  // 32*1024 f32 = 128 KiB
    float* scores = (float*)((char*)d_ws + (size_t)B_DIM * H_DIM * sizeof(float));

    hipMemsetAsync(v, 0, (size_t)B_DIM * H_DIM * sizeof(float), stream);
    compute_v_kernel<<<dim3(H_DIM / 256, B_DIM, KSPLIT), 256, 0, stream>>>(hidden, W, v);
    compute_scores_kernel<<<dim3(T_DIM / 8, B_DIM), 256, 0, stream>>>(enc, v, scores);
    softmax_kernel<<<B_DIM, 256, 0, stream>>>(scores, out);
}